// Round 2
// baseline (527.074 us; speedup 1.0000x reference)
//
#include <hip/hip_runtime.h>
#include <math.h>

#define E_DIM 128
#define R_DIM 128
#define N_REL 64
#define REG_LAMBDA 1e-5f

#define NSEG 16      // segments per relation -> grid = 64*16 = 1024 blocks
#define GG 8         // samples per chunk
#define GEPI 4       // samples per epilogue round (epi buffer sizing)
#define LISTMAX 512  // slice size = ceil(8192/16) = 512

// Relation-grouped kernel, v3.
// Thread t: q = t>>5 owns e-range [32q,32q+32); u = t&31 owns cols 4u..4u+3.
// Per chunk of GG samples: each W float4 (kept in regs) feeds 8 samples x 3
// vectors; each LDS b128 read feeds 16 FMAs (was 1 float/FMA in v2 -> LDS-bound).
// Cross-q partial sums reduced through a small LDS buffer in 2 rounds.
__global__ void __launch_bounds__(128, 2)
kge_grouped3(const int* __restrict__ h_idx, const int* __restrict__ r_idx,
             const int* __restrict__ pt_idx, const int* __restrict__ nt_idx,
             const float* __restrict__ ent,   // (N_ENT, 128)
             const float* __restrict__ rel,   // (64, 128)
             const float* __restrict__ W,     // (64, 128, 128)
             float* __restrict__ per_sample,  // (M,)
             int M)
{
    const int t      = threadIdx.x;          // 0..127
    const int rel_id = blockIdx.x >> 4;      // 0..63
    const int seg    = blockIdx.x & (NSEG - 1);
    const int q      = t >> 5;               // e-split group 0..3
    const int u      = t & 31;               // column group
    const int c4     = u << 2;               // first owned column

    __shared__ int s_cnt;
    __shared__ int s_list[LISTMAX];
    __shared__ __align__(16) float sh[GG][E_DIM];
    __shared__ __align__(16) float sp[GG][E_DIM];
    __shared__ __align__(16) float sn[GG][E_DIM];
    __shared__ __align__(16) float epi[GEPI][3][4][E_DIM]; // [g][vec][q][col]
    __shared__ float wpart[3][GG][2];

    const int range = (M + NSEG - 1) / NSEG;
    const int m0 = seg * range;
    const int m1 = min(m0 + range, M);

    // ---- scan my slice of r[] for samples with my relation ----
    if (t == 0) s_cnt = 0;
    __syncthreads();
    for (int m = m0 + t; m < m1; m += 128) {
        if (r_idx[m] == rel_id) {
            int p = atomicAdd(&s_cnt, 1);
            if (p < LISTMAX) s_list[p] = m;
        }
    }
    __syncthreads();
    const int cnt = s_cnt;
    if (cnt == 0) return;

    const float* __restrict__ Wq = W + (size_t)rel_id * (E_DIM * R_DIM);
    const float re = rel[(size_t)rel_id * R_DIM + t];

    for (int c0 = 0; c0 < cnt; c0 += GG) {
        // ---- stage GG sample triples into LDS (pad by duplicating last) ----
#pragma unroll
        for (int g = 0; g < GG; ++g) {
            int sl = c0 + g; if (sl > cnt - 1) sl = cnt - 1;
            int m = s_list[sl];
            sh[g][t] = ent[(size_t)h_idx[m]  * E_DIM + t];
            sp[g][t] = ent[(size_t)pt_idx[m] * E_DIM + t];
            sn[g][t] = ent[(size_t)nt_idx[m] * E_DIM + t];
        }
        __syncthreads();  // staging visible; also orders prior-chunk sh reads

        float aH[GG][4], aP[GG][4], aN[GG][4];
#pragma unroll
        for (int g = 0; g < GG; ++g)
#pragma unroll
            for (int c = 0; c < 4; ++c) { aH[g][c] = 0.f; aP[g][c] = 0.f; aN[g][c] = 0.f; }

        const int eBase = q << 5;
        // ---- main loop: 8 steps of 4 e's; W quad in regs, 16 FMA per b128 ----
#pragma unroll
        for (int es = 0; es < 8; ++es) {
            const int e0 = eBase + (es << 2);
            const float4 W0 = *(const float4*)&Wq[(size_t)(e0 + 0) * R_DIM + c4];
            const float4 W1 = *(const float4*)&Wq[(size_t)(e0 + 1) * R_DIM + c4];
            const float4 W2 = *(const float4*)&Wq[(size_t)(e0 + 2) * R_DIM + c4];
            const float4 W3 = *(const float4*)&Wq[(size_t)(e0 + 3) * R_DIM + c4];
            const float w0[4] = {W0.x, W0.y, W0.z, W0.w};
            const float w1[4] = {W1.x, W1.y, W1.z, W1.w};
            const float w2[4] = {W2.x, W2.y, W2.z, W2.w};
            const float w3[4] = {W3.x, W3.y, W3.z, W3.w};
#pragma unroll
            for (int g = 0; g < GG; ++g) {
                const float4 h4 = *(const float4*)&sh[g][e0];
                const float4 p4 = *(const float4*)&sp[g][e0];
                const float4 n4 = *(const float4*)&sn[g][e0];
#pragma unroll
                for (int c = 0; c < 4; ++c) {
                    aH[g][c] = fmaf(h4.x, w0[c], aH[g][c]);
                    aH[g][c] = fmaf(h4.y, w1[c], aH[g][c]);
                    aH[g][c] = fmaf(h4.z, w2[c], aH[g][c]);
                    aH[g][c] = fmaf(h4.w, w3[c], aH[g][c]);
                    aP[g][c] = fmaf(p4.x, w0[c], aP[g][c]);
                    aP[g][c] = fmaf(p4.y, w1[c], aP[g][c]);
                    aP[g][c] = fmaf(p4.z, w2[c], aP[g][c]);
                    aP[g][c] = fmaf(p4.w, w3[c], aP[g][c]);
                    aN[g][c] = fmaf(n4.x, w0[c], aN[g][c]);
                    aN[g][c] = fmaf(n4.y, w1[c], aN[g][c]);
                    aN[g][c] = fmaf(n4.z, w2[c], aN[g][c]);
                    aN[g][c] = fmaf(n4.w, w3[c], aN[g][c]);
                }
            }
        }

        // ---- epilogue: cross-q reduce through LDS, 2 rounds of GEPI ----
#pragma unroll
        for (int r0 = 0; r0 < GG; r0 += GEPI) {
            __syncthreads();  // prior round's epi reads done before overwrite
#pragma unroll
            for (int g = 0; g < GEPI; ++g) {
                const int gg = r0 + g;
                *(float4*)&epi[g][0][q][c4] = make_float4(aH[gg][0], aH[gg][1], aH[gg][2], aH[gg][3]);
                *(float4*)&epi[g][1][q][c4] = make_float4(aP[gg][0], aP[gg][1], aP[gg][2], aP[gg][3]);
                *(float4*)&epi[g][2][q][c4] = make_float4(aN[gg][0], aN[gg][1], aN[gg][2], aN[gg][3]);
            }
            __syncthreads();  // epi visible
#pragma unroll
            for (int g = 0; g < GEPI; ++g) {
                const int gg = r0 + g;
                float hv = ((epi[g][0][0][t] + epi[g][0][1][t]) + epi[g][0][2][t]) + epi[g][0][3][t];
                float pv = ((epi[g][1][0][t] + epi[g][1][1][t]) + epi[g][1][2][t]) + epi[g][1][3][t];
                float nv = ((epi[g][2][0][t] + epi[g][2][1][t]) + epi[g][2][2][t]) + epi[g][2][3][t];
                float he = sh[gg][t], pe = sp[gg][t], ne = sn[gg][t];
                float a  = hv + re;
                float dp = a - pv;
                float dn = a - nv;
                float pos = dp * dp;
                float neg = dn * dn;
                float reg = he * he + re * re + pe * pe + ne * ne;
#pragma unroll
                for (int off = 32; off > 0; off >>= 1) {
                    pos += __shfl_down(pos, off);
                    neg += __shfl_down(neg, off);
                    reg += __shfl_down(reg, off);
                }
                if ((t & 63) == 0) {
                    wpart[0][gg][t >> 6] = pos;
                    wpart[1][gg][t >> 6] = neg;
                    wpart[2][gg][t >> 6] = reg;
                }
            }
        }
        __syncthreads();  // wpart visible
        if (t < GG && (c0 + t) < cnt) {
            float P = wpart[0][t][0] + wpart[0][t][1];
            float N = wpart[1][t][0] + wpart[1][t][1];
            float R = wpart[2][t][0] + wpart[2][t][1];
            float diff = 0.5f * (P - N);            // pos_score - neg_score
            float z = -diff;                        // -log_sigmoid = softplus(-diff)
            float sp_v = fmaxf(z, 0.f) + log1pf(expf(-fabsf(z)));
            per_sample[s_list[c0 + t]] = sp_v + REG_LAMBDA * 0.5f * R;
        }
    }
}

// Single-block final reduction -> mean (unchanged)
__global__ void __launch_bounds__(256)
kge_reduce_kernel(const float* __restrict__ per_sample, float* __restrict__ out, int M)
{
    int t = threadIdx.x;
    float s = 0.f;
    for (int i = t; i < M; i += 256) s += per_sample[i];
#pragma unroll
    for (int off = 32; off > 0; off >>= 1) s += __shfl_down(s, off);
    __shared__ float part[4];
    if ((t & 63) == 0) part[t >> 6] = s;
    __syncthreads();
    if (t == 0) out[0] = (part[0] + part[1] + part[2] + part[3]) / (float)M;
}

extern "C" void kernel_launch(void* const* d_in, const int* in_sizes, int n_in,
                              void* d_out, int out_size, void* d_ws, size_t ws_size,
                              hipStream_t stream)
{
    const int*   h_idx  = (const int*)d_in[0];
    const int*   r_idx  = (const int*)d_in[1];
    const int*   pt_idx = (const int*)d_in[2];
    const int*   nt_idx = (const int*)d_in[3];
    const float* ent    = (const float*)d_in[4];
    const float* rel    = (const float*)d_in[5];
    const float* W      = (const float*)d_in[6];
    float* out = (float*)d_out;

    int M = in_sizes[0];
    float* per_sample = (float*)d_ws;  // M floats

    kge_grouped3<<<N_REL * NSEG, 128, 0, stream>>>(h_idx, r_idx, pt_idx, nt_idx,
                                                   ent, rel, W, per_sample, M);
    kge_reduce_kernel<<<1, 256, 0, stream>>>(per_sample, out, M);
}

// Round 3
// 340.813 us; speedup vs baseline: 1.5465x; 1.5465x over previous
//
#include <hip/hip_runtime.h>
#include <math.h>

#define E_DIM 128
#define R_DIM 128
#define N_REL 64
#define REG_LAMBDA 1e-5f

#define NSEG 16      // segments per relation -> grid = 64*16 = 1024 blocks (4/CU)
#define G 4          // samples per chunk (register tile: 3*4*2 = 24 accumulators)
#define LISTMAX 256  // >> max samples per (relation,segment) for uniform r

// v4: 256 threads = 4 waves. Wave q owns e-quarter [32q,32q+32); lane u=t&63
// owns cols 2u,2u+1. Per chunk of G=4 samples: each W float2 (from L2, in regs)
// feeds 12 FMAs; each LDS broadcast float4 feeds 8 FMAs. Cross-wave partials
// combined through a small LDS buffer. Register tile kept at 24 accumulators
// (v3's 96-acc tile spilled: 373 MB/dispatch scratch writes).
__global__ void __launch_bounds__(256)
kge_grouped4(const int* __restrict__ h_idx, const int* __restrict__ r_idx,
             const int* __restrict__ pt_idx, const int* __restrict__ nt_idx,
             const float* __restrict__ ent,   // (N_ENT, 128)
             const float* __restrict__ rel,   // (64, 128)
             const float* __restrict__ W,     // (64, 128, 128)
             float* __restrict__ per_sample,  // (M,)
             int M)
{
    const int t      = threadIdx.x;          // 0..255
    const int rel_id = blockIdx.x >> 4;      // 0..63
    const int seg    = blockIdx.x & (NSEG - 1);
    const int q      = t >> 6;               // wave id 0..3 -> e-quarter
    const int u      = t & 63;               // col-pair index
    const int cb     = u << 1;               // first owned column

    __shared__ int s_cnt;
    __shared__ int s_list[LISTMAX];
    __shared__ __align__(16) float sh[G][E_DIM];
    __shared__ __align__(16) float sp[G][E_DIM];
    __shared__ __align__(16) float sn[G][E_DIM];
    __shared__ __align__(16) float epi[G][3][4][R_DIM];  // [g][vec][waveq][col]
    __shared__ float wpart[3][G][2];

    const int range = (M + NSEG - 1) / NSEG;
    const int m0 = seg * range;
    const int m1 = min(m0 + range, M);

    // ---- scan my slice of r[] for samples with my relation ----
    if (t == 0) s_cnt = 0;
    __syncthreads();
    for (int m = m0 + t; m < m1; m += 256) {
        if (r_idx[m] == rel_id) {
            int p = atomicAdd(&s_cnt, 1);
            if (p < LISTMAX) s_list[p] = m;
        }
    }
    __syncthreads();
    const int cnt = min(s_cnt, LISTMAX);
    if (cnt == 0) return;

    // wave-q slice of W_r, offset to this lane's column pair
    const float* __restrict__ Wq =
        W + (size_t)rel_id * (E_DIM * R_DIM) + (size_t)(q << 5) * R_DIM + cb;
    const float re = (t < E_DIM) ? rel[(size_t)rel_id * R_DIM + t] : 0.f;

    const int elem = t & 127;   // staging: element index
    const int half = t >> 7;    // staging: which g's this half handles

    for (int c0 = 0; c0 < cnt; c0 += G) {
        // ---- stage G sample triples into LDS (pad by duplicating last) ----
        for (int g = half; g < G; g += 2) {
            int sl = c0 + g; if (sl > cnt - 1) sl = cnt - 1;
            int m = s_list[sl];
            sh[g][elem] = ent[(size_t)h_idx[m]  * E_DIM + elem];
            sp[g][elem] = ent[(size_t)pt_idx[m] * E_DIM + elem];
            sn[g][elem] = ent[(size_t)nt_idx[m] * E_DIM + elem];
        }
        __syncthreads();  // staging visible (also fences prior-iter LDS reads)

        float aH[G][2], aP[G][2], aN[G][2];
#pragma unroll
        for (int g = 0; g < G; ++g) {
            aH[g][0] = 0.f; aH[g][1] = 0.f;
            aP[g][0] = 0.f; aP[g][1] = 0.f;
            aN[g][0] = 0.f; aN[g][1] = 0.f;
        }

        const int eBase = q << 5;
        // ---- main loop: 8 steps of 4 e's over this wave's quarter ----
#pragma unroll 2
        for (int es = 0; es < 8; ++es) {
            const int e0 = eBase + (es << 2);
            const float2 w0 = *(const float2*)(Wq + (size_t)((es << 2) + 0) * R_DIM);
            const float2 w1 = *(const float2*)(Wq + (size_t)((es << 2) + 1) * R_DIM);
            const float2 w2 = *(const float2*)(Wq + (size_t)((es << 2) + 2) * R_DIM);
            const float2 w3 = *(const float2*)(Wq + (size_t)((es << 2) + 3) * R_DIM);
#pragma unroll
            for (int g = 0; g < G; ++g) {
                const float4 h4 = *(const float4*)&sh[g][e0];
                const float4 p4 = *(const float4*)&sp[g][e0];
                const float4 n4 = *(const float4*)&sn[g][e0];
                aH[g][0] = fmaf(h4.x, w0.x, aH[g][0]);
                aH[g][0] = fmaf(h4.y, w1.x, aH[g][0]);
                aH[g][0] = fmaf(h4.z, w2.x, aH[g][0]);
                aH[g][0] = fmaf(h4.w, w3.x, aH[g][0]);
                aH[g][1] = fmaf(h4.x, w0.y, aH[g][1]);
                aH[g][1] = fmaf(h4.y, w1.y, aH[g][1]);
                aH[g][1] = fmaf(h4.z, w2.y, aH[g][1]);
                aH[g][1] = fmaf(h4.w, w3.y, aH[g][1]);
                aP[g][0] = fmaf(p4.x, w0.x, aP[g][0]);
                aP[g][0] = fmaf(p4.y, w1.x, aP[g][0]);
                aP[g][0] = fmaf(p4.z, w2.x, aP[g][0]);
                aP[g][0] = fmaf(p4.w, w3.x, aP[g][0]);
                aP[g][1] = fmaf(p4.x, w0.y, aP[g][1]);
                aP[g][1] = fmaf(p4.y, w1.y, aP[g][1]);
                aP[g][1] = fmaf(p4.z, w2.y, aP[g][1]);
                aP[g][1] = fmaf(p4.w, w3.y, aP[g][1]);
                aN[g][0] = fmaf(n4.x, w0.x, aN[g][0]);
                aN[g][0] = fmaf(n4.y, w1.x, aN[g][0]);
                aN[g][0] = fmaf(n4.z, w2.x, aN[g][0]);
                aN[g][0] = fmaf(n4.w, w3.x, aN[g][0]);
                aN[g][1] = fmaf(n4.x, w0.y, aN[g][1]);
                aN[g][1] = fmaf(n4.y, w1.y, aN[g][1]);
                aN[g][1] = fmaf(n4.z, w2.y, aN[g][1]);
                aN[g][1] = fmaf(n4.w, w3.y, aN[g][1]);
            }
        }

        // ---- cross-wave partial sums through LDS ----
#pragma unroll
        for (int g = 0; g < G; ++g) {
            *(float2*)&epi[g][0][q][cb] = make_float2(aH[g][0], aH[g][1]);
            *(float2*)&epi[g][1][q][cb] = make_float2(aP[g][0], aP[g][1]);
            *(float2*)&epi[g][2][q][cb] = make_float2(aN[g][0], aN[g][1]);
        }
        __syncthreads();  // epi visible

        if (t < E_DIM) {  // waves 0,1 finalize; col = t
#pragma unroll
            for (int g = 0; g < G; ++g) {
                float hv = (epi[g][0][0][t] + epi[g][0][1][t]) + (epi[g][0][2][t] + epi[g][0][3][t]);
                float pv = (epi[g][1][0][t] + epi[g][1][1][t]) + (epi[g][1][2][t] + epi[g][1][3][t]);
                float nv = (epi[g][2][0][t] + epi[g][2][1][t]) + (epi[g][2][2][t] + epi[g][2][3][t]);
                float he = sh[g][t], pe = sp[g][t], ne = sn[g][t];
                float a  = hv + re;
                float dp = a - pv;
                float dn = a - nv;
                float pos = dp * dp;
                float neg = dn * dn;
                float reg = he * he + re * re + pe * pe + ne * ne;
#pragma unroll
                for (int off = 32; off > 0; off >>= 1) {
                    pos += __shfl_down(pos, off);
                    neg += __shfl_down(neg, off);
                    reg += __shfl_down(reg, off);
                }
                if ((t & 63) == 0) {
                    wpart[0][g][t >> 6] = pos;
                    wpart[1][g][t >> 6] = neg;
                    wpart[2][g][t >> 6] = reg;
                }
            }
        }
        __syncthreads();  // wpart visible

        if (t < G && (c0 + t) < cnt) {
            float P  = wpart[0][t][0] + wpart[0][t][1];
            float Nn = wpart[1][t][0] + wpart[1][t][1];
            float R  = wpart[2][t][0] + wpart[2][t][1];
            float diff = 0.5f * (P - Nn);           // pos_score - neg_score
            float z = -diff;                        // -log_sigmoid = softplus(-diff)
            float sp_v = fmaxf(z, 0.f) + log1pf(expf(-fabsf(z)));
            per_sample[s_list[c0 + t]] = sp_v + REG_LAMBDA * 0.5f * R;
        }
        // next-iter staging is fenced from this iter's sh/epi reads by the
        // wpart barrier above; wpart reads are fenced from next writes by the
        // next staging barrier.
    }
}

// Single-block final reduction -> mean
__global__ void __launch_bounds__(256)
kge_reduce_kernel(const float* __restrict__ per_sample, float* __restrict__ out, int M)
{
    int t = threadIdx.x;
    float s = 0.f;
    for (int i = t; i < M; i += 256) s += per_sample[i];
#pragma unroll
    for (int off = 32; off > 0; off >>= 1) s += __shfl_down(s, off);
    __shared__ float part[4];
    if ((t & 63) == 0) part[t >> 6] = s;
    __syncthreads();
    if (t == 0) out[0] = (part[0] + part[1] + part[2] + part[3]) / (float)M;
}

extern "C" void kernel_launch(void* const* d_in, const int* in_sizes, int n_in,
                              void* d_out, int out_size, void* d_ws, size_t ws_size,
                              hipStream_t stream)
{
    const int*   h_idx  = (const int*)d_in[0];
    const int*   r_idx  = (const int*)d_in[1];
    const int*   pt_idx = (const int*)d_in[2];
    const int*   nt_idx = (const int*)d_in[3];
    const float* ent    = (const float*)d_in[4];
    const float* rel    = (const float*)d_in[5];
    const float* W      = (const float*)d_in[6];
    float* out = (float*)d_out;

    int M = in_sizes[0];
    float* per_sample = (float*)d_ws;  // M floats

    kge_grouped4<<<N_REL * NSEG, 256, 0, stream>>>(h_idx, r_idx, pt_idx, nt_idx,
                                                   ent, rel, W, per_sample, M);
    kge_reduce_kernel<<<1, 256, 0, stream>>>(per_sample, out, M);
}